// Round 14
// baseline (443.020 us; speedup 1.0000x reference)
//
#include <hip/hip_runtime.h>
#include <hip/hip_bf16.h>
#include <math.h>

#define NT   65536      // total nodes (32 graphs * 2048)
#define NPGC 2048       // nodes per graph
#define NG   32         // graphs
#define NE   524288     // edges
#define HID  128

typedef short short8 __attribute__((ext_vector_type(8)));
typedef float f32x4  __attribute__((ext_vector_type(4)));

__device__ __forceinline__ float bf2f(unsigned short u) {
    union { unsigned int i; float f; } v; v.i = ((unsigned int)u) << 16; return v.f;
}
__device__ __forceinline__ unsigned short f2bf(float f) {   // round-to-nearest (packW only)
    union { float f; unsigned int i; } v; v.f = f;
    unsigned int x = v.i;
    return (unsigned short)((x + 0x7fffu + ((x >> 16) & 1u)) >> 16);
}
// fast truncation split: v ~ hi + lo, |err| <= 2^-16 |v| (4 ops)
__device__ __forceinline__ void split2(float v, unsigned short& hi, unsigned short& lo) {
    unsigned int b = __float_as_uint(v);
    hi = (unsigned short)(b >> 16);
    float rem = v - __uint_as_float(b & 0xFFFF0000u);
    lo = (unsigned short)(__float_as_uint(rem) >> 16);
}

// ---------- dtype detection: bf16 vs fp32 ----------
__global__ void k_detect(const unsigned short* __restrict__ x, int* __restrict__ flag) {
    __shared__ int cnt;
    if (threadIdx.x == 0) cnt = 0;
    __syncthreads();
    int sane = 0;
#pragma unroll
    for (int j = 0; j < 16; ++j) {
        unsigned short u = x[threadIdx.x * 16 + j];
        int e = (u >> 7) & 0xFF;
        if (e > 0x60 && e < 0xA0) sane++;
    }
    atomicAdd(&cnt, sane);
    __syncthreads();
    if (threadIdx.x == 0) *flag = (cnt > 3686) ? 1 : 0;
}

// ---------- weight conversion: (bf16|f32) -> f32 scratch ----------
struct CvtDesc { const void* src[22]; int n[22]; int off[22]; };

__global__ void k_cvt(CvtDesc d, float* __restrict__ wts, const int* __restrict__ flag) {
    int t = blockIdx.y;
    int n = d.n[t];
    bool isbf = (*flag != 0);
    const unsigned short* sb = (const unsigned short*)d.src[t];
    const float* sf = (const float*)d.src[t];
    float* o = wts + d.off[t];
    for (int i = blockIdx.x * blockDim.x + threadIdx.x; i < n; i += gridDim.x * blockDim.x)
        o[i] = isbf ? bf2f(sb[i]) : sf[i];
}

// ---------- pack SAGE weights (+ zero rowc/fill for the CSR build) ----------
__global__ void k_packW(const float* __restrict__ wts, int4 oWl, int4 oWr,
                        unsigned short* __restrict__ Wpack,
                        int* __restrict__ rowc, int* __restrict__ fill) {
    int idx = blockIdx.x * 256 + threadIdx.x;
    if (idx < NT) { rowc[idx] = 0; fill[idx] = 0; }
    if (idx >= 4 * 8 * 8 * 64 * 8) return;
    int L    = idx >> 15;
    int rem  = idx & 32767;
    int ct   = rem >> 12;
    int rem2 = rem & 4095;
    int ks   = rem2 >> 9;
    int rem3 = rem2 & 511;
    int lane = rem3 >> 3;
    int j    = rem3 & 7;
    int k   = ks * 32 + (lane >> 4) * 8 + j;
    int col = ct * 16 + (lane & 15);
    int ol = (L == 0) ? oWl.x : (L == 1) ? oWl.y : (L == 2) ? oWl.z : oWl.w;
    int orr = (L == 0) ? oWr.x : (L == 1) ? oWr.y : (L == 2) ? oWr.z : oWr.w;
    float w = (k < 128) ? wts[ol + k * 128 + col] : wts[orr + (k - 128) * 128 + col];
    unsigned short hi = f2bf(w);
    unsigned short lo = f2bf(w - bf2f(hi));
    int base = L * 65536 + (ct * 8 + ks) * 512 + lane * 8 + j;
    Wpack[base]         = hi;
    Wpack[base + 32768] = lo;
}

// ---------- load x -> f32 only if bf16 (+ init nm, + edge histogram) ----------
__global__ void k_load_x(const void* __restrict__ x, float* __restrict__ out,
                         const int* __restrict__ flag, int n4,
                         float* __restrict__ nm, const int* __restrict__ dstE,
                         int* __restrict__ rowc) {
    int i = blockIdx.x * blockDim.x + threadIdx.x;
    if (i < NT) nm[i] = 1.0f;
    if (i < NE) atomicAdd(&rowc[dstE[i]], 1);
    if (i >= n4) return;
    if (*flag) {
        ushort4 v = ((const ushort4*)x)[i];
        float4 o;
        o.x = bf2f(v.x); o.y = bf2f(v.y); o.z = bf2f(v.z); o.w = bf2f(v.w);
        ((float4*)out)[i] = o;
    }
}

// scan1 also emits initial invc (nm==1 -> invc = 1/max(deg,1))
__global__ void k_scan1(const int* __restrict__ cnt, int* __restrict__ rp, int* __restrict__ bsum,
                        float* __restrict__ invc) {
    __shared__ int s[256];
    int t = threadIdx.x;
    int i = blockIdx.x * 256 + t;
    int v = cnt[i];
    invc[i] = 1.0f / fmaxf((float)v, 1.0f);
    s[t] = v;
    __syncthreads();
    for (int off = 1; off < 256; off <<= 1) {
        int a = (t >= off) ? s[t - off] : 0;
        __syncthreads();
        s[t] += a;
        __syncthreads();
    }
    rp[i] = s[t] - v;
    if (t == 255) bsum[blockIdx.x] = s[255];
}

// merged scan2+scan3
__global__ void k_scan23(int* __restrict__ rp, const int* __restrict__ bsum) {
    __shared__ int s[256];
    int t = threadIdx.x;
    s[t] = bsum[t];
    __syncthreads();
    for (int off = 1; off < 256; off <<= 1) {
        int a = (t >= off) ? s[t - off] : 0;
        __syncthreads();
        s[t] += a;
        __syncthreads();
    }
    int boffv = s[blockIdx.x] - bsum[blockIdx.x];
    int i = blockIdx.x * 256 + t;
    rp[i] += boffv;
    if (i == 0) rp[NT] = NE;
}

__global__ void k_scatter(const int* __restrict__ src, const int* __restrict__ dst,
                          const int* __restrict__ rp, int* __restrict__ fill, int* __restrict__ col) {
    int e = blockIdx.x * blockDim.x + threadIdx.x;
    if (e < NE) {
        int d = dst[e];
        int p = rp[d] + atomicAdd(&fill[d], 1);
        col[p] = src[e];
    }
}

// ---------- invc[n] = 1 / max(sum_in nm[col], 1) (wide) ----------
__global__ void k_invc(const float* __restrict__ nm, const int* __restrict__ rp,
                       const int* __restrict__ col, float* __restrict__ invc) {
    int n = blockIdx.x * 256 + threadIdx.x;
    int beg = rp[n], end = rp[n + 1];
    float c = 0.f;
    for (int e = beg; e < end; ++e) c += nm[col[e]];
    invc[n] = 1.0f / fmaxf(c, 1.0f);
}

// ---------- LDS swizzle ----------
__device__ __forceinline__ int lds_sw(int node, int k) {
    int g = k >> 3;
    int go = g ^ (node & 7);
    return node * 128 + go * 8 + (k & 7);
}

// ---------- shared body: phases A/B + MFMA; root rows prefetched to registers ----------
template<bool HAS_TS>
__device__ __forceinline__ void sage_body(
    const float* __restrict__ h, const float* __restrict__ ts,
    const float* __restrict__ nm, const float* __restrict__ invc,
    const int* __restrict__ rp, const int* __restrict__ col,
    const unsigned short* __restrict__ Wp,
    unsigned short* Ahi, unsigned short* Alo,
    int n0, int tid, f32x4 acc[2][2])
{
    int lane = tid & 63, w = tid >> 6;
    int lrow = lane & 15, quad = lane >> 4;

    // ---- prefetch root rows into registers (overlaps with gather below) ----
    float4 rootv[4];
#pragma unroll
    for (int i = 0; i < 4; ++i) {
        int idx = i * 256 + tid;
        int node = idx >> 5;
        int f = (idx & 31) * 4;
        int gn = n0 + node;
        float4 v = *(const float4*)&h[(size_t)gn * HID + f];
        float sc = HAS_TS ? ts[gn] : 1.0f;
        v.x *= sc; v.y *= sc; v.z *= sc; v.w *= sc;
        rootv[i] = v;
    }

    // ---- phase A: gather mean rows (K 0..127), 4 edges in flight ----
#pragma unroll
    for (int pass = 0; pass < 4; ++pass) {
        int node = pass * 8 + (tid >> 5);
        int f = (tid & 31) * 4;
        int gn = n0 + node;
        float ax = 0.f, ay = 0.f, az = 0.f, aw = 0.f;
        if (nm[gn] > 0.f) {
            int beg = rp[gn], end = rp[gn + 1];
            for (int e0 = beg; e0 < end; e0 += 4) {
                int ecl = end - 1;
                int e1 = (e0 + 1 < end) ? e0 + 1 : ecl;
                int e2 = (e0 + 2 < end) ? e0 + 2 : ecl;
                int e3 = (e0 + 3 < end) ? e0 + 3 : ecl;
                int s0 = col[e0], s1 = col[e1], s2 = col[e2], s3 = col[e3];
                float4 v0 = *(const float4*)&h[(size_t)s0 * HID + f];
                float4 v1 = *(const float4*)&h[(size_t)s1 * HID + f];
                float4 v2 = *(const float4*)&h[(size_t)s2 * HID + f];
                float4 v3 = *(const float4*)&h[(size_t)s3 * HID + f];
                float c0 = HAS_TS ? ts[s0] : 1.0f;
                float c1 = (e0 + 1 < end) ? (HAS_TS ? ts[s1] : 1.0f) : 0.0f;
                float c2 = (e0 + 2 < end) ? (HAS_TS ? ts[s2] : 1.0f) : 0.0f;
                float c3 = (e0 + 3 < end) ? (HAS_TS ? ts[s3] : 1.0f) : 0.0f;
                ax += v0.x * c0 + v1.x * c1 + v2.x * c2 + v3.x * c3;
                ay += v0.y * c0 + v1.y * c1 + v2.y * c2 + v3.y * c3;
                az += v0.z * c0 + v1.z * c1 + v2.z * c2 + v3.z * c3;
                aw += v0.w * c0 + v1.w * c1 + v2.w * c2 + v3.w * c3;
            }
        }
        float inv = invc[gn];
        ushort4 hi4, lo4;
        split2(ax * inv, hi4.x, lo4.x);
        split2(ay * inv, hi4.y, lo4.y);
        split2(az * inv, hi4.z, lo4.z);
        split2(aw * inv, hi4.w, lo4.w);
        int a = lds_sw(node, f);
        *(ushort4*)&Ahi[a] = hi4;
        *(ushort4*)&Alo[a] = lo4;
    }
    __syncthreads();

    // ---- MFMA over Wl half (ks 0..3, from LDS) ----
#pragma unroll
    for (int ks = 0; ks < 4; ++ks) {
        short8 bh[2], blo[2];
#pragma unroll
        for (int c = 0; c < 2; ++c) {
            int ct = 2 * w + c;
            bh[c]  = *(const short8*)&Wp[(ct * 8 + ks) * 512 + lane * 8];
            blo[c] = *(const short8*)&Wp[32768 + (ct * 8 + ks) * 512 + lane * 8];
        }
        int kb = ks * 32 + quad * 8;
#pragma unroll
        for (int st = 0; st < 2; ++st) {
            int a = lds_sw(st * 16 + lrow, kb);
            short8 ah = *(const short8*)&Ahi[a];
            short8 al = *(const short8*)&Alo[a];
#pragma unroll
            for (int c = 0; c < 2; ++c) {
                acc[st][c] = __builtin_amdgcn_mfma_f32_16x16x32_bf16(ah, bh[c],  acc[st][c], 0, 0, 0);
                acc[st][c] = __builtin_amdgcn_mfma_f32_16x16x32_bf16(al, bh[c],  acc[st][c], 0, 0, 0);
                acc[st][c] = __builtin_amdgcn_mfma_f32_16x16x32_bf16(ah, blo[c], acc[st][c], 0, 0, 0);
            }
        }
    }
    __syncthreads();

    // ---- phase B: write prefetched root rows (no loads here) ----
#pragma unroll
    for (int i = 0; i < 4; ++i) {
        int idx = i * 256 + tid;
        int node = idx >> 5;
        int f = (idx & 31) * 4;
        ushort4 hi4, lo4;
        split2(rootv[i].x, hi4.x, lo4.x);
        split2(rootv[i].y, hi4.y, lo4.y);
        split2(rootv[i].z, hi4.z, lo4.z);
        split2(rootv[i].w, hi4.w, lo4.w);
        int a = lds_sw(node, f);
        *(ushort4*)&Ahi[a] = hi4;
        *(ushort4*)&Alo[a] = lo4;
    }
    __syncthreads();

    // ---- MFMA over Wr half (ks 4..7, from LDS) ----
#pragma unroll
    for (int ks = 4; ks < 8; ++ks) {
        short8 bh[2], blo[2];
#pragma unroll
        for (int c = 0; c < 2; ++c) {
            int ct = 2 * w + c;
            bh[c]  = *(const short8*)&Wp[(ct * 8 + ks) * 512 + lane * 8];
            blo[c] = *(const short8*)&Wp[32768 + (ct * 8 + ks) * 512 + lane * 8];
        }
        int kb = (ks - 4) * 32 + quad * 8;
#pragma unroll
        for (int st = 0; st < 2; ++st) {
            int a = lds_sw(st * 16 + lrow, kb);
            short8 ah = *(const short8*)&Ahi[a];
            short8 al = *(const short8*)&Alo[a];
#pragma unroll
            for (int c = 0; c < 2; ++c) {
                acc[st][c] = __builtin_amdgcn_mfma_f32_16x16x32_bf16(ah, bh[c],  acc[st][c], 0, 0, 0);
                acc[st][c] = __builtin_amdgcn_mfma_f32_16x16x32_bf16(al, bh[c],  acc[st][c], 0, 0, 0);
                acc[st][c] = __builtin_amdgcn_mfma_f32_16x16x32_bf16(ah, blo[c], acc[st][c], 0, 0, 0);
            }
        }
    }
}

// ---------- plain fused SAGE layer (layers 1 & 3) ----------
template<bool HAS_TS>
__global__ void __launch_bounds__(256, 8) k_sage_plain(
    const float* __restrict__ h, const void* __restrict__ xraw, const int* __restrict__ flag,
    const float* __restrict__ ts,
    const float* __restrict__ nm, const float* __restrict__ invc,
    const int* __restrict__ rp, const int* __restrict__ col,
    const unsigned short* __restrict__ Wp, const float* __restrict__ bl,
    float* __restrict__ out)
{
    __shared__ unsigned short Ahi[32 * 128];
    __shared__ unsigned short Alo[32 * 128];
    int tid = threadIdx.x;
    int b = blockIdx.x;
    int graph = (b & 7) * 4 + (b >> 9);
    int tile  = (b >> 3) & 63;
    int n0 = graph * NPGC + tile * 32;
    int lane = tid & 63, w = tid >> 6;
    int lrow = lane & 15, quad = lane >> 4;
    f32x4 acc[2][2] = {};

    const float* hh = h;
    if (xraw && *flag == 0) hh = (const float*)xraw;

    sage_body<HAS_TS>(hh, ts, nm, invc, rp, col, Wp, Ahi, Alo, n0, tid, acc);

#pragma unroll
    for (int c = 0; c < 2; ++c) {
        int colg = (2 * w + c) * 16 + lrow;
        float bias = bl[colg];
#pragma unroll
        for (int st = 0; st < 2; ++st) {
#pragma unroll
            for (int rr = 0; rr < 4; ++rr) {
                int node = n0 + st * 16 + quad * 4 + rr;
                float val = fmaxf(acc[st][c][rr] + bias, 0.f) * nm[node];
                out[(size_t)node * HID + colg] = val;
            }
        }
    }
}

// ---------- fused SAGE layer + pool dots (layers 2 & 4, no ts) ----------
__global__ void __launch_bounds__(256, 8) k_sage_dots(
    const float* __restrict__ h,
    const float* __restrict__ nm, const float* __restrict__ invc,
    const int* __restrict__ rp, const int* __restrict__ col,
    const unsigned short* __restrict__ Wp, const float* __restrict__ bl,
    float* __restrict__ out,
    const float* __restrict__ Prel, const float* __restrict__ Proot,
    float* __restrict__ q, float* __restrict__ r)
{
    __shared__ unsigned short Ahi[32 * 128];
    __shared__ unsigned short Alo[32 * 128];
    int tid = threadIdx.x;
    int b = blockIdx.x;
    int graph = (b & 7) * 4 + (b >> 9);
    int tile  = (b >> 3) & 63;
    int n0 = graph * NPGC + tile * 32;
    int lane = tid & 63, w = tid >> 6;
    int lrow = lane & 15, quad = lane >> 4;
    f32x4 acc[2][2] = {};

    sage_body<false>(h, nullptr, nm, invc, rp, col, Wp, Ahi, Alo, n0, tid, acc);

    float qp[2][4] = {}, rp_[2][4] = {};
#pragma unroll
    for (int c = 0; c < 2; ++c) {
        int colg = (2 * w + c) * 16 + lrow;
        float bias = bl[colg];
        float pq = Prel[colg], pr = Proot[colg];
#pragma unroll
        for (int st = 0; st < 2; ++st) {
#pragma unroll
            for (int rr = 0; rr < 4; ++rr) {
                int node = n0 + st * 16 + quad * 4 + rr;
                float val = fmaxf(acc[st][c][rr] + bias, 0.f) * nm[node];
                out[(size_t)node * HID + colg] = val;
                qp[st][rr] += val * pq;
                rp_[st][rr] += val * pr;
            }
        }
    }
#pragma unroll
    for (int st = 0; st < 2; ++st)
#pragma unroll
        for (int rr = 0; rr < 4; ++rr) {
#pragma unroll
            for (int m = 1; m < 16; m <<= 1) {
                qp[st][rr]  += __shfl_xor(qp[st][rr],  m, 64);
                rp_[st][rr] += __shfl_xor(rp_[st][rr], m, 64);
            }
        }
    __syncthreads();
    float* qa = (float*)Ahi;
    if (tid < 64) qa[tid] = 0.f;
    __syncthreads();
    if (lrow == 0) {
#pragma unroll
        for (int st = 0; st < 2; ++st)
#pragma unroll
            for (int rr = 0; rr < 4; ++rr) {
                int nl = st * 16 + quad * 4 + rr;
                atomicAdd(&qa[nl], qp[st][rr]);
                atomicAdd(&qa[32 + nl], rp_[st][rr]);
            }
    }
    __syncthreads();
    if (tid < 32) {
        q[n0 + tid] = qa[tid];
        r[n0 + tid] = qa[32 + tid];
    }
}

// ---------- score = segsum(q[src]) + r + prb (wide) ----------
__global__ void k_score(const float* __restrict__ q, const float* __restrict__ r,
                        const float* __restrict__ prb,
                        const int* __restrict__ rp, const int* __restrict__ col,
                        float* __restrict__ score) {
    int n = blockIdx.x * 256 + threadIdx.x;
    int beg = rp[n], end = rp[n + 1];
    float s = 0.f;
    for (int e = beg; e < end; ++e) s += q[col[e]];
    score[n] = s + r[n] + prb[0];
}

// ---------- per-graph top-k via radix select (shuffle scans, ~14 syncs) ----------
__global__ void __launch_bounds__(256) k_topk(const float* __restrict__ score,
                                              float* __restrict__ nm,
                                              float* __restrict__ tval, int k) {
    __shared__ unsigned int u[NPGC];
    __shared__ int hist[256];
    __shared__ int scanb[257];
    __shared__ int wtot[4];
    __shared__ unsigned int s_byte;
    __shared__ int s_kk;
    int tid = threadIdx.x;
    int lane = tid & 63, wv = tid >> 6;
    int base = blockIdx.x * NPGC;

    for (int j = tid; j < NPGC; j += 256) {
        float sc = (nm[base + j] > 0.f) ? score[base + j] : -1e30f;
        unsigned int v = __float_as_uint(sc);
        v = (v & 0x80000000u) ? ~v : (v | 0x80000000u);
        u[j] = v;
    }
    hist[tid] = 0;
    if (tid == 0) scanb[256] = 0;
    __syncthreads();

    unsigned int prefix = 0;
    int kk = k;
#pragma unroll
    for (int round = 0; round < 4; ++round) {
        int shift = 24 - 8 * round;
        unsigned int pmask = (round == 0) ? 0u : (0xFFFFFFFFu << (32 - 8 * round));
        for (int j = tid; j < NPGC; j += 256) {
            unsigned int v = u[j];
            if ((v & pmask) == prefix) atomicAdd(&hist[(v >> shift) & 0xFF], 1);
        }
        __syncthreads();
        int s = hist[tid];
        // inclusive suffix sum within wave (64 bins per wave)
#pragma unroll
        for (int off = 1; off < 64; off <<= 1) {
            int t = __shfl_down(s, off, 64);
            s += (lane + off < 64) ? t : 0;
        }
        if (lane == 0) wtot[wv] = s;
        __syncthreads();
        int add = 0;
#pragma unroll
        for (int w2 = 1; w2 < 4; ++w2) add += (wv + w2 < 4) ? wtot[wv + w2] : 0;
        s += add;
        scanb[tid] = s;
        __syncthreads();
        int above = scanb[tid + 1];
        if (s >= kk && above < kk) { s_byte = (unsigned int)tid; s_kk = kk - above; }
        hist[tid] = 0;   // own-slot re-zero for next round
        __syncthreads();
        prefix |= (s_byte << shift);
        kk = s_kk;
    }
    unsigned int thr = prefix;

    // tie-break: exclusive prefix of ==thr counts, lowest index first
    int j0 = tid * 8;
    int cnt = 0;
#pragma unroll
    for (int j = 0; j < 8; ++j) cnt += (u[j0 + j] == thr);
    int s = cnt;
#pragma unroll
    for (int off = 1; off < 64; off <<= 1) {
        int t = __shfl_up(s, off, 64);
        s += (lane >= off) ? t : 0;
    }
    if (lane == 63) wtot[wv] = s;
    __syncthreads();
    int add = 0;
#pragma unroll
    for (int w2 = 0; w2 < 4; ++w2) add += (w2 < wv) ? wtot[w2] : 0;
    int rank = s - cnt + add;
#pragma unroll
    for (int j = 0; j < 8; ++j) {
        unsigned int v = u[j0 + j];
        bool keep;
        if (v > thr) keep = true;
        else if (v == thr) { keep = (rank < kk); rank++; }
        else keep = false;
        nm[base + j0 + j]   = keep ? 1.0f : 0.0f;
        tval[base + j0 + j] = keep ? tanhf(score[base + j0 + j]) : 0.0f;
    }
}

// ---------- per-graph sum of h*t (parallel partials via atomics) ----------
__global__ void k_gsum(const float* __restrict__ h, const float* __restrict__ t,
                       const float* __restrict__ nm,
                       float* __restrict__ g, float* __restrict__ gcnt) {
    int b = blockIdx.x;
    int graph = b >> 4, part = b & 15;
    int f = threadIdx.x & 127, sub = threadIdx.x >> 7;
    int nbase = graph * NPGC + part * 128 + sub * 64;
    float acc = 0.f;
#pragma unroll 4
    for (int n = 0; n < 64; ++n)
        acc += h[(size_t)(nbase + n) * HID + f] * t[nbase + n];
    atomicAdd(&g[graph * HID + f], acc);
    if (threadIdx.x < 64 && sub == 0) {
        float cnt = 0.f;
        int cb = graph * NPGC + part * 128;
        for (int n = threadIdx.x; n < 128; n += 64) cnt += nm[cb + n];
        for (int o = 32; o > 0; o >>= 1) cnt += __shfl_down(cnt, o, 64);
        if (threadIdx.x == 0) atomicAdd(&gcnt[graph], cnt);
    }
}

// ---------- MLP head + log_softmax (gdiv fused) ----------
__global__ void k_mlp(const float* __restrict__ g, const float* __restrict__ gcnt,
                      const float* __restrict__ W5,
                      const float* __restrict__ b5, const float* __restrict__ W6,
                      const float* __restrict__ b6, void* __restrict__ out,
                      const int* __restrict__ flag) {
    __shared__ float g5[64];
    __shared__ float ls[2];
    int graph = blockIdx.x, j = threadIdx.x;
    float ic = 1.0f / fmaxf(gcnt[graph], 1.0f);
    float acc = b5[j];
    for (int f = 0; f < HID; ++f)
        acc += (g[graph * HID + f] * ic) * W5[f * 64 + j];
    g5[j] = fmaxf(acc, 0.f);
    __syncthreads();
    if (j < 2) {
        float l = b6[j];
        for (int t = 0; t < 64; ++t) l += g5[t] * W6[t * 2 + j];
        ls[j] = l;
    }
    __syncthreads();
    if (j == 0) {
        float a = ls[0], b = ls[1];
        float mx = fmaxf(a, b);
        float lse = mx + logf(expf(a - mx) + expf(b - mx));
        if (*flag) {
            ((unsigned short*)out)[graph * 2 + 0] = f2bf(a - lse);
            ((unsigned short*)out)[graph * 2 + 1] = f2bf(b - lse);
        } else {
            ((float*)out)[graph * 2 + 0] = a - lse;
            ((float*)out)[graph * 2 + 1] = b - lse;
        }
    }
}

extern "C" void kernel_launch(void* const* d_in, const int* in_sizes, int n_in,
                              void* d_out, int out_size, void* d_ws, size_t ws_size,
                              hipStream_t stream) {
    const void* x    = d_in[0];
    const int*  ei   = (const int*)d_in[1];
    const int*  srcE = ei;
    const int*  dstE = ei + NE;

    char* ws = (char*)d_ws;
    float* hA    = (float*)(ws + 0);
    float* hB    = (float*)(ws + 33554432);
    float* tvec  = (float*)(ws + 67108864);
    float* invc  = (float*)(ws + 67371008);
    float* q     = (float*)(ws + 100663296);
    float* r     = (float*)(ws + 100925440);
    float* score = (float*)(ws + 101187584);
    float* nm    = (float*)(ws + 101449728);
    int*   rowc  = (int*)  (ws + 101711872);
    int*   rp    = (int*)  (ws + 101974016);
    int*   bsum  = (int*)  (ws + 102236416);
    int*   fill  = (int*)  (ws + 102238464);
    int*   col   = (int*)  (ws + 102500608);
    float* g     = (float*)(ws + 104597760);
    float* gcnt  = (float*)(ws + 104614144);
    int*   flag  = (int*)  (ws + 104615936);
    float* wts   = (float*)(ws + 104616960);
    unsigned short* Wpack = (unsigned short*)(ws + 105179136);
    (void)in_sizes; (void)n_in; (void)out_size; (void)ws_size;

    const int O_Wl1 = 0,      O_bl1 = 16384,  O_Wr1 = 16512;
    const int O_Wl2 = 32896,  O_bl2 = 49280,  O_Wr2 = 49408;
    const int O_Wl3 = 65792,  O_bl3 = 82176,  O_Wr3 = 82304;
    const int O_Wl4 = 98688,  O_bl4 = 115072, O_Wr4 = 115200;
    const int O_Pr1 = 131584, O_pb1 = 131712, O_Po1 = 131713;
    const int O_Pr2 = 131841, O_pb2 = 131969, O_Po2 = 131970;
    const int O_W5  = 132098, O_b5  = 140290, O_W6 = 140354, O_b6 = 140482;

    CvtDesc d;
    const int srcIdx[22] = {4,5,6,7,8,9,10,11,12,13,14,15,16,17,18,19,20,21,22,23,24,25};
    const int nelems[22] = {16384,128,16384, 16384,128,16384, 16384,128,16384, 16384,128,16384,
                            128,1,128, 128,1,128, 8192,64,128,2};
    const int offs[22]   = {O_Wl1,O_bl1,O_Wr1, O_Wl2,O_bl2,O_Wr2, O_Wl3,O_bl3,O_Wr3, O_Wl4,O_bl4,O_Wr4,
                            O_Pr1,O_pb1,O_Po1, O_Pr2,O_pb2,O_Po2, O_W5,O_b5,O_W6,O_b6};
    for (int i = 0; i < 22; ++i) { d.src[i] = d_in[srcIdx[i]]; d.n[i] = nelems[i]; d.off[i] = offs[i]; }

    hipMemsetAsync(g, 0, (NG * HID + NG + 64) * 4, stream);

    k_detect <<<1, 256, 0, stream>>>((const unsigned short*)x, flag);
    k_cvt    <<<dim3(64, 22), 256, 0, stream>>>(d, wts, flag);
    k_packW  <<<512, 256, 0, stream>>>(wts, make_int4(O_Wl1, O_Wl2, O_Wl3, O_Wl4),
                                       make_int4(O_Wr1, O_Wr2, O_Wr3, O_Wr4), Wpack, rowc, fill);
    k_load_x <<<8192, 256, 0, stream>>>(x, hA, flag, NT * HID / 4, nm, dstE, rowc);

    k_scan1  <<<256, 256, 0, stream>>>(rowc, rp, bsum, invc);
    k_scan23 <<<256, 256, 0, stream>>>(rp, bsum);
    k_scatter<<<2048, 256, 0, stream>>>(srcE, dstE, rp, fill, col);

    // layer 1: x/hA -> hB (reads x directly when fp32 input)
    k_sage_plain<false><<<2048, 256, 0, stream>>>(hA, x, flag, nullptr, nm, invc, rp, col,
                                                  Wpack + 0 * 65536, wts + O_bl1, hB);
    // layer 2: hB -> hA  (+ fused pool-1 dots)
    k_sage_dots<<<2048, 256, 0, stream>>>(hB, nm, invc, rp, col,
                                          Wpack + 1 * 65536, wts + O_bl2, hA,
                                          wts + O_Pr1, wts + O_Po1, q, r);

    // pool 1 (k = 1024)
    k_score<<<256, 256, 0, stream>>>(q, r, wts + O_pb1, rp, col, score);
    k_topk <<<32, 256, 0, stream>>>(score, nm, tvec, 1024);
    k_invc <<<256, 256, 0, stream>>>(nm, rp, col, invc);

    // layer 3: hA (scaled by tvec) -> hB
    k_sage_plain<true><<<2048, 256, 0, stream>>>(hA, nullptr, flag, tvec, nm, invc, rp, col,
                                                 Wpack + 2 * 65536, wts + O_bl3, hB);
    // layer 4: hB -> hA  (+ fused pool-2 dots)
    k_sage_dots<<<2048, 256, 0, stream>>>(hB, nm, invc, rp, col,
                                          Wpack + 3 * 65536, wts + O_bl4, hA,
                                          wts + O_Pr2, wts + O_Po2, q, r);

    // pool 2 (k = 512)
    k_score<<<256, 256, 0, stream>>>(q, r, wts + O_pb2, rp, col, score);
    k_topk <<<32, 256, 0, stream>>>(score, nm, tvec, 512);

    // readout (h*t folded in)
    k_gsum<<<512, 256, 0, stream>>>(hA, tvec, nm, g, gcnt);
    k_mlp <<<32, 64, 0, stream>>>(g, gcnt, wts + O_W5, wts + O_b5, wts + O_W6, wts + O_b6, d_out, flag);
}

// Round 15
// 385.147 us; speedup vs baseline: 1.1503x; 1.1503x over previous
//
#include <hip/hip_runtime.h>
#include <hip/hip_bf16.h>
#include <math.h>

#define NT   65536      // total nodes (32 graphs * 2048)
#define NPGC 2048       // nodes per graph
#define NG   32         // graphs
#define NE   524288     // edges
#define HID  128

typedef short short8 __attribute__((ext_vector_type(8)));
typedef float f32x4  __attribute__((ext_vector_type(4)));

__device__ __forceinline__ float bf2f(unsigned short u) {
    union { unsigned int i; float f; } v; v.i = ((unsigned int)u) << 16; return v.f;
}
__device__ __forceinline__ unsigned short f2bf(float f) {   // round-to-nearest (packW only)
    union { float f; unsigned int i; } v; v.f = f;
    unsigned int x = v.i;
    return (unsigned short)((x + 0x7fffu + ((x >> 16) & 1u)) >> 16);
}
// fast truncation split: v ~ hi + lo, |err| <= 2^-16 |v| (4 ops)
__device__ __forceinline__ void split2(float v, unsigned short& hi, unsigned short& lo) {
    unsigned int b = __float_as_uint(v);
    hi = (unsigned short)(b >> 16);
    float rem = v - __uint_as_float(b & 0xFFFF0000u);
    lo = (unsigned short)(__float_as_uint(rem) >> 16);
}

// ---------- dtype detection: bf16 vs fp32 ----------
__global__ void k_detect(const unsigned short* __restrict__ x, int* __restrict__ flag) {
    __shared__ int cnt;
    if (threadIdx.x == 0) cnt = 0;
    __syncthreads();
    int sane = 0;
#pragma unroll
    for (int j = 0; j < 16; ++j) {
        unsigned short u = x[threadIdx.x * 16 + j];
        int e = (u >> 7) & 0xFF;
        if (e > 0x60 && e < 0xA0) sane++;
    }
    atomicAdd(&cnt, sane);
    __syncthreads();
    if (threadIdx.x == 0) *flag = (cnt > 3686) ? 1 : 0;
}

// ---------- weight conversion: (bf16|f32) -> f32 scratch ----------
struct CvtDesc { const void* src[22]; int n[22]; int off[22]; };

__global__ void k_cvt(CvtDesc d, float* __restrict__ wts, const int* __restrict__ flag) {
    int t = blockIdx.y;
    int n = d.n[t];
    bool isbf = (*flag != 0);
    const unsigned short* sb = (const unsigned short*)d.src[t];
    const float* sf = (const float*)d.src[t];
    float* o = wts + d.off[t];
    for (int i = blockIdx.x * blockDim.x + threadIdx.x; i < n; i += gridDim.x * blockDim.x)
        o[i] = isbf ? bf2f(sb[i]) : sf[i];
}

// ---------- pack SAGE weights (+ zero rowc/fill for the CSR build) ----------
__global__ void k_packW(const float* __restrict__ wts, int4 oWl, int4 oWr,
                        unsigned short* __restrict__ Wpack,
                        int* __restrict__ rowc, int* __restrict__ fill) {
    int idx = blockIdx.x * 256 + threadIdx.x;
    if (idx < NT) { rowc[idx] = 0; fill[idx] = 0; }
    if (idx >= 4 * 8 * 8 * 64 * 8) return;
    int L    = idx >> 15;
    int rem  = idx & 32767;
    int ct   = rem >> 12;
    int rem2 = rem & 4095;
    int ks   = rem2 >> 9;
    int rem3 = rem2 & 511;
    int lane = rem3 >> 3;
    int j    = rem3 & 7;
    int k   = ks * 32 + (lane >> 4) * 8 + j;
    int col = ct * 16 + (lane & 15);
    int ol = (L == 0) ? oWl.x : (L == 1) ? oWl.y : (L == 2) ? oWl.z : oWl.w;
    int orr = (L == 0) ? oWr.x : (L == 1) ? oWr.y : (L == 2) ? oWr.z : oWr.w;
    float w = (k < 128) ? wts[ol + k * 128 + col] : wts[orr + (k - 128) * 128 + col];
    unsigned short hi = f2bf(w);
    unsigned short lo = f2bf(w - bf2f(hi));
    int base = L * 65536 + (ct * 8 + ks) * 512 + lane * 8 + j;
    Wpack[base]         = hi;
    Wpack[base + 32768] = lo;
}

// ---------- load x -> f32 only if bf16 (+ init nm, + edge histogram) ----------
__global__ void k_load_x(const void* __restrict__ x, float* __restrict__ out,
                         const int* __restrict__ flag, int n4,
                         float* __restrict__ nm, const int* __restrict__ dstE,
                         int* __restrict__ rowc) {
    int i = blockIdx.x * blockDim.x + threadIdx.x;
    if (i < NT) nm[i] = 1.0f;
    if (i < NE) atomicAdd(&rowc[dstE[i]], 1);
    if (i >= n4) return;
    if (*flag) {
        ushort4 v = ((const ushort4*)x)[i];
        float4 o;
        o.x = bf2f(v.x); o.y = bf2f(v.y); o.z = bf2f(v.z); o.w = bf2f(v.w);
        ((float4*)out)[i] = o;
    }
}

// scan1 also emits initial invc (nm==1 -> invc = 1/max(deg,1))
__global__ void k_scan1(const int* __restrict__ cnt, int* __restrict__ rp, int* __restrict__ bsum,
                        float* __restrict__ invc) {
    __shared__ int s[256];
    int t = threadIdx.x;
    int i = blockIdx.x * 256 + t;
    int v = cnt[i];
    invc[i] = 1.0f / fmaxf((float)v, 1.0f);
    s[t] = v;
    __syncthreads();
    for (int off = 1; off < 256; off <<= 1) {
        int a = (t >= off) ? s[t - off] : 0;
        __syncthreads();
        s[t] += a;
        __syncthreads();
    }
    rp[i] = s[t] - v;
    if (t == 255) bsum[blockIdx.x] = s[255];
}

// merged scan2+scan3
__global__ void k_scan23(int* __restrict__ rp, const int* __restrict__ bsum) {
    __shared__ int s[256];
    int t = threadIdx.x;
    s[t] = bsum[t];
    __syncthreads();
    for (int off = 1; off < 256; off <<= 1) {
        int a = (t >= off) ? s[t - off] : 0;
        __syncthreads();
        s[t] += a;
        __syncthreads();
    }
    int boffv = s[blockIdx.x] - bsum[blockIdx.x];
    int i = blockIdx.x * 256 + t;
    rp[i] += boffv;
    if (i == 0) rp[NT] = NE;
}

__global__ void k_scatter(const int* __restrict__ src, const int* __restrict__ dst,
                          const int* __restrict__ rp, int* __restrict__ fill, int* __restrict__ col) {
    int e = blockIdx.x * blockDim.x + threadIdx.x;
    if (e < NE) {
        int d = dst[e];
        int p = rp[d] + atomicAdd(&fill[d], 1);
        col[p] = src[e];
    }
}

// ---------- invc[n] = 1 / max(sum_in nm[col], 1) (wide) ----------
__global__ void k_invc(const float* __restrict__ nm, const int* __restrict__ rp,
                       const int* __restrict__ col, float* __restrict__ invc) {
    int n = blockIdx.x * 256 + threadIdx.x;
    int beg = rp[n], end = rp[n + 1];
    float c = 0.f;
    for (int e = beg; e < end; ++e) c += nm[col[e]];
    invc[n] = 1.0f / fmaxf(c, 1.0f);
}

// ---------- LDS swizzle ----------
__device__ __forceinline__ int lds_sw(int node, int k) {
    int g = k >> 3;
    int go = g ^ (node & 7);
    return node * 128 + go * 8 + (k & 7);
}

// ---------- shared body: phases A/B + MFMA (R13 structure; no reg prefetch) ----------
template<bool HAS_TS>
__device__ __forceinline__ void sage_body(
    const float* __restrict__ h, const float* __restrict__ ts,
    const float* __restrict__ nm, const float* __restrict__ invc,
    const int* __restrict__ rp, const int* __restrict__ col,
    const unsigned short* __restrict__ Wp,
    unsigned short* Ahi, unsigned short* Alo,
    int n0, int tid, f32x4 acc[2][2])
{
    int lane = tid & 63, w = tid >> 6;
    int lrow = lane & 15, quad = lane >> 4;

    // ---- phase A: gather mean rows (K 0..127), 4 edges in flight ----
#pragma unroll
    for (int pass = 0; pass < 4; ++pass) {
        int node = pass * 8 + (tid >> 5);
        int f = (tid & 31) * 4;
        int gn = n0 + node;
        float ax = 0.f, ay = 0.f, az = 0.f, aw = 0.f;
        if (nm[gn] > 0.f) {
            int beg = rp[gn], end = rp[gn + 1];
            for (int e0 = beg; e0 < end; e0 += 4) {
                int ecl = end - 1;
                int e1 = (e0 + 1 < end) ? e0 + 1 : ecl;
                int e2 = (e0 + 2 < end) ? e0 + 2 : ecl;
                int e3 = (e0 + 3 < end) ? e0 + 3 : ecl;
                int s0 = col[e0], s1 = col[e1], s2 = col[e2], s3 = col[e3];
                float4 v0 = *(const float4*)&h[(size_t)s0 * HID + f];
                float4 v1 = *(const float4*)&h[(size_t)s1 * HID + f];
                float4 v2 = *(const float4*)&h[(size_t)s2 * HID + f];
                float4 v3 = *(const float4*)&h[(size_t)s3 * HID + f];
                float c0 = HAS_TS ? ts[s0] : 1.0f;
                float c1 = (e0 + 1 < end) ? (HAS_TS ? ts[s1] : 1.0f) : 0.0f;
                float c2 = (e0 + 2 < end) ? (HAS_TS ? ts[s2] : 1.0f) : 0.0f;
                float c3 = (e0 + 3 < end) ? (HAS_TS ? ts[s3] : 1.0f) : 0.0f;
                ax += v0.x * c0 + v1.x * c1 + v2.x * c2 + v3.x * c3;
                ay += v0.y * c0 + v1.y * c1 + v2.y * c2 + v3.y * c3;
                az += v0.z * c0 + v1.z * c1 + v2.z * c2 + v3.z * c3;
                aw += v0.w * c0 + v1.w * c1 + v2.w * c2 + v3.w * c3;
            }
        }
        float inv = invc[gn];
        ushort4 hi4, lo4;
        split2(ax * inv, hi4.x, lo4.x);
        split2(ay * inv, hi4.y, lo4.y);
        split2(az * inv, hi4.z, lo4.z);
        split2(aw * inv, hi4.w, lo4.w);
        int a = lds_sw(node, f);
        *(ushort4*)&Ahi[a] = hi4;
        *(ushort4*)&Alo[a] = lo4;
    }
    __syncthreads();

    // ---- MFMA over Wl half (ks 0..3, from LDS) ----
#pragma unroll
    for (int ks = 0; ks < 4; ++ks) {
        short8 bh[2], blo[2];
#pragma unroll
        for (int c = 0; c < 2; ++c) {
            int ct = 2 * w + c;
            bh[c]  = *(const short8*)&Wp[(ct * 8 + ks) * 512 + lane * 8];
            blo[c] = *(const short8*)&Wp[32768 + (ct * 8 + ks) * 512 + lane * 8];
        }
        int kb = ks * 32 + quad * 8;
#pragma unroll
        for (int st = 0; st < 2; ++st) {
            int a = lds_sw(st * 16 + lrow, kb);
            short8 ah = *(const short8*)&Ahi[a];
            short8 al = *(const short8*)&Alo[a];
#pragma unroll
            for (int c = 0; c < 2; ++c) {
                acc[st][c] = __builtin_amdgcn_mfma_f32_16x16x32_bf16(ah, bh[c],  acc[st][c], 0, 0, 0);
                acc[st][c] = __builtin_amdgcn_mfma_f32_16x16x32_bf16(al, bh[c],  acc[st][c], 0, 0, 0);
                acc[st][c] = __builtin_amdgcn_mfma_f32_16x16x32_bf16(ah, blo[c], acc[st][c], 0, 0, 0);
            }
        }
    }
    __syncthreads();

    // ---- phase B: stage root h rows (K 128..255 -> local 0..127), coalesced ----
#pragma unroll
    for (int i = 0; i < 4; ++i) {
        int idx = i * 256 + tid;
        int node = idx >> 5;
        int f = (idx & 31) * 4;
        int gn = n0 + node;
        float4 v = *(const float4*)&h[(size_t)gn * HID + f];
        float sc = HAS_TS ? ts[gn] : 1.0f;
        ushort4 hi4, lo4;
        split2(v.x * sc, hi4.x, lo4.x);
        split2(v.y * sc, hi4.y, lo4.y);
        split2(v.z * sc, hi4.z, lo4.z);
        split2(v.w * sc, hi4.w, lo4.w);
        int a = lds_sw(node, f);
        *(ushort4*)&Ahi[a] = hi4;
        *(ushort4*)&Alo[a] = lo4;
    }
    __syncthreads();

    // ---- MFMA over Wr half (ks 4..7, from LDS) ----
#pragma unroll
    for (int ks = 4; ks < 8; ++ks) {
        short8 bh[2], blo[2];
#pragma unroll
        for (int c = 0; c < 2; ++c) {
            int ct = 2 * w + c;
            bh[c]  = *(const short8*)&Wp[(ct * 8 + ks) * 512 + lane * 8];
            blo[c] = *(const short8*)&Wp[32768 + (ct * 8 + ks) * 512 + lane * 8];
        }
        int kb = (ks - 4) * 32 + quad * 8;
#pragma unroll
        for (int st = 0; st < 2; ++st) {
            int a = lds_sw(st * 16 + lrow, kb);
            short8 ah = *(const short8*)&Ahi[a];
            short8 al = *(const short8*)&Alo[a];
#pragma unroll
            for (int c = 0; c < 2; ++c) {
                acc[st][c] = __builtin_amdgcn_mfma_f32_16x16x32_bf16(ah, bh[c],  acc[st][c], 0, 0, 0);
                acc[st][c] = __builtin_amdgcn_mfma_f32_16x16x32_bf16(al, bh[c],  acc[st][c], 0, 0, 0);
                acc[st][c] = __builtin_amdgcn_mfma_f32_16x16x32_bf16(ah, blo[c], acc[st][c], 0, 0, 0);
            }
        }
    }
}

// ---------- plain fused SAGE layer (layers 1 & 3) ----------
template<bool HAS_TS>
__global__ void __launch_bounds__(256, 8) k_sage_plain(
    const float* __restrict__ h, const void* __restrict__ xraw, const int* __restrict__ flag,
    const float* __restrict__ ts,
    const float* __restrict__ nm, const float* __restrict__ invc,
    const int* __restrict__ rp, const int* __restrict__ col,
    const unsigned short* __restrict__ Wp, const float* __restrict__ bl,
    float* __restrict__ out)
{
    __shared__ unsigned short Ahi[32 * 128];
    __shared__ unsigned short Alo[32 * 128];
    int tid = threadIdx.x;
    int b = blockIdx.x;
    int graph = (b & 7) * 4 + (b >> 9);
    int tile  = (b >> 3) & 63;
    int n0 = graph * NPGC + tile * 32;
    int lane = tid & 63, w = tid >> 6;
    int lrow = lane & 15, quad = lane >> 4;
    f32x4 acc[2][2] = {};

    const float* hh = h;
    if (xraw && *flag == 0) hh = (const float*)xraw;

    sage_body<HAS_TS>(hh, ts, nm, invc, rp, col, Wp, Ahi, Alo, n0, tid, acc);

#pragma unroll
    for (int c = 0; c < 2; ++c) {
        int colg = (2 * w + c) * 16 + lrow;
        float bias = bl[colg];
#pragma unroll
        for (int st = 0; st < 2; ++st) {
#pragma unroll
            for (int rr = 0; rr < 4; ++rr) {
                int node = n0 + st * 16 + quad * 4 + rr;
                float val = fmaxf(acc[st][c][rr] + bias, 0.f) * nm[node];
                out[(size_t)node * HID + colg] = val;
            }
        }
    }
}

// ---------- fused SAGE layer + pool dots (layers 2 & 4, no ts) ----------
__global__ void __launch_bounds__(256, 8) k_sage_dots(
    const float* __restrict__ h,
    const float* __restrict__ nm, const float* __restrict__ invc,
    const int* __restrict__ rp, const int* __restrict__ col,
    const unsigned short* __restrict__ Wp, const float* __restrict__ bl,
    float* __restrict__ out,
    const float* __restrict__ Prel, const float* __restrict__ Proot,
    float* __restrict__ q, float* __restrict__ r)
{
    __shared__ unsigned short Ahi[32 * 128];
    __shared__ unsigned short Alo[32 * 128];
    int tid = threadIdx.x;
    int b = blockIdx.x;
    int graph = (b & 7) * 4 + (b >> 9);
    int tile  = (b >> 3) & 63;
    int n0 = graph * NPGC + tile * 32;
    int lane = tid & 63, w = tid >> 6;
    int lrow = lane & 15, quad = lane >> 4;
    f32x4 acc[2][2] = {};

    sage_body<false>(h, nullptr, nm, invc, rp, col, Wp, Ahi, Alo, n0, tid, acc);

    float qp[2][4] = {}, rp_[2][4] = {};
#pragma unroll
    for (int c = 0; c < 2; ++c) {
        int colg = (2 * w + c) * 16 + lrow;
        float bias = bl[colg];
        float pq = Prel[colg], pr = Proot[colg];
#pragma unroll
        for (int st = 0; st < 2; ++st) {
#pragma unroll
            for (int rr = 0; rr < 4; ++rr) {
                int node = n0 + st * 16 + quad * 4 + rr;
                float val = fmaxf(acc[st][c][rr] + bias, 0.f) * nm[node];
                out[(size_t)node * HID + colg] = val;
                qp[st][rr] += val * pq;
                rp_[st][rr] += val * pr;
            }
        }
    }
#pragma unroll
    for (int st = 0; st < 2; ++st)
#pragma unroll
        for (int rr = 0; rr < 4; ++rr) {
#pragma unroll
            for (int m = 1; m < 16; m <<= 1) {
                qp[st][rr]  += __shfl_xor(qp[st][rr],  m, 64);
                rp_[st][rr] += __shfl_xor(rp_[st][rr], m, 64);
            }
        }
    __syncthreads();
    float* qa = (float*)Ahi;
    if (tid < 64) qa[tid] = 0.f;
    __syncthreads();
    if (lrow == 0) {
#pragma unroll
        for (int st = 0; st < 2; ++st)
#pragma unroll
            for (int rr = 0; rr < 4; ++rr) {
                int nl = st * 16 + quad * 4 + rr;
                atomicAdd(&qa[nl], qp[st][rr]);
                atomicAdd(&qa[32 + nl], rp_[st][rr]);
            }
    }
    __syncthreads();
    if (tid < 32) {
        q[n0 + tid] = qa[tid];
        r[n0 + tid] = qa[32 + tid];
    }
}

// ---------- score = segsum(q[src]) + r + prb (wide) ----------
__global__ void k_score(const float* __restrict__ q, const float* __restrict__ r,
                        const float* __restrict__ prb,
                        const int* __restrict__ rp, const int* __restrict__ col,
                        float* __restrict__ score) {
    int n = blockIdx.x * 256 + threadIdx.x;
    int beg = rp[n], end = rp[n + 1];
    float s = 0.f;
    for (int e = beg; e < end; ++e) s += q[col[e]];
    score[n] = s + r[n] + prb[0];
}

// ---------- per-graph top-k via radix select (shuffle scans, ~14 syncs) ----------
__global__ void __launch_bounds__(256) k_topk(const float* __restrict__ score,
                                              float* __restrict__ nm,
                                              float* __restrict__ tval, int k) {
    __shared__ unsigned int u[NPGC];
    __shared__ int hist[256];
    __shared__ int scanb[257];
    __shared__ int wtot[4];
    __shared__ unsigned int s_byte;
    __shared__ int s_kk;
    int tid = threadIdx.x;
    int lane = tid & 63, wv = tid >> 6;
    int base = blockIdx.x * NPGC;

    for (int j = tid; j < NPGC; j += 256) {
        float sc = (nm[base + j] > 0.f) ? score[base + j] : -1e30f;
        unsigned int v = __float_as_uint(sc);
        v = (v & 0x80000000u) ? ~v : (v | 0x80000000u);
        u[j] = v;
    }
    hist[tid] = 0;
    if (tid == 0) scanb[256] = 0;
    __syncthreads();

    unsigned int prefix = 0;
    int kk = k;
#pragma unroll
    for (int round = 0; round < 4; ++round) {
        int shift = 24 - 8 * round;
        unsigned int pmask = (round == 0) ? 0u : (0xFFFFFFFFu << (32 - 8 * round));
        for (int j = tid; j < NPGC; j += 256) {
            unsigned int v = u[j];
            if ((v & pmask) == prefix) atomicAdd(&hist[(v >> shift) & 0xFF], 1);
        }
        __syncthreads();
        int s = hist[tid];
#pragma unroll
        for (int off = 1; off < 64; off <<= 1) {
            int t = __shfl_down(s, off, 64);
            s += (lane + off < 64) ? t : 0;
        }
        if (lane == 0) wtot[wv] = s;
        __syncthreads();
        int add = 0;
#pragma unroll
        for (int w2 = 1; w2 < 4; ++w2) add += (wv + w2 < 4) ? wtot[wv + w2] : 0;
        s += add;
        scanb[tid] = s;
        __syncthreads();
        int above = scanb[tid + 1];
        if (s >= kk && above < kk) { s_byte = (unsigned int)tid; s_kk = kk - above; }
        hist[tid] = 0;
        __syncthreads();
        prefix |= (s_byte << shift);
        kk = s_kk;
    }
    unsigned int thr = prefix;

    int j0 = tid * 8;
    int cnt = 0;
#pragma unroll
    for (int j = 0; j < 8; ++j) cnt += (u[j0 + j] == thr);
    int s = cnt;
#pragma unroll
    for (int off = 1; off < 64; off <<= 1) {
        int t = __shfl_up(s, off, 64);
        s += (lane >= off) ? t : 0;
    }
    if (lane == 63) wtot[wv] = s;
    __syncthreads();
    int add = 0;
#pragma unroll
    for (int w2 = 0; w2 < 4; ++w2) add += (w2 < wv) ? wtot[w2] : 0;
    int rank = s - cnt + add;
#pragma unroll
    for (int j = 0; j < 8; ++j) {
        unsigned int v = u[j0 + j];
        bool keep;
        if (v > thr) keep = true;
        else if (v == thr) { keep = (rank < kk); rank++; }
        else keep = false;
        nm[base + j0 + j]   = keep ? 1.0f : 0.0f;
        tval[base + j0 + j] = keep ? tanhf(score[base + j0 + j]) : 0.0f;
    }
}

// ---------- per-graph sum of h*t (parallel partials via atomics) ----------
__global__ void k_gsum(const float* __restrict__ h, const float* __restrict__ t,
                       const float* __restrict__ nm,
                       float* __restrict__ g, float* __restrict__ gcnt) {
    int b = blockIdx.x;
    int graph = b >> 4, part = b & 15;
    int f = threadIdx.x & 127, sub = threadIdx.x >> 7;
    int nbase = graph * NPGC + part * 128 + sub * 64;
    float acc = 0.f;
#pragma unroll 4
    for (int n = 0; n < 64; ++n)
        acc += h[(size_t)(nbase + n) * HID + f] * t[nbase + n];
    atomicAdd(&g[graph * HID + f], acc);
    if (threadIdx.x < 64 && sub == 0) {
        float cnt = 0.f;
        int cb = graph * NPGC + part * 128;
        for (int n = threadIdx.x; n < 128; n += 64) cnt += nm[cb + n];
        for (int o = 32; o > 0; o >>= 1) cnt += __shfl_down(cnt, o, 64);
        if (threadIdx.x == 0) atomicAdd(&gcnt[graph], cnt);
    }
}

// ---------- MLP head + log_softmax (gdiv fused) ----------
__global__ void k_mlp(const float* __restrict__ g, const float* __restrict__ gcnt,
                      const float* __restrict__ W5,
                      const float* __restrict__ b5, const float* __restrict__ W6,
                      const float* __restrict__ b6, void* __restrict__ out,
                      const int* __restrict__ flag) {
    __shared__ float g5[64];
    __shared__ float ls[2];
    int graph = blockIdx.x, j = threadIdx.x;
    float ic = 1.0f / fmaxf(gcnt[graph], 1.0f);
    float acc = b5[j];
    for (int f = 0; f < HID; ++f)
        acc += (g[graph * HID + f] * ic) * W5[f * 64 + j];
    g5[j] = fmaxf(acc, 0.f);
    __syncthreads();
    if (j < 2) {
        float l = b6[j];
        for (int t = 0; t < 64; ++t) l += g5[t] * W6[t * 2 + j];
        ls[j] = l;
    }
    __syncthreads();
    if (j == 0) {
        float a = ls[0], b = ls[1];
        float mx = fmaxf(a, b);
        float lse = mx + logf(expf(a - mx) + expf(b - mx));
        if (*flag) {
            ((unsigned short*)out)[graph * 2 + 0] = f2bf(a - lse);
            ((unsigned short*)out)[graph * 2 + 1] = f2bf(b - lse);
        } else {
            ((float*)out)[graph * 2 + 0] = a - lse;
            ((float*)out)[graph * 2 + 1] = b - lse;
        }
    }
}

extern "C" void kernel_launch(void* const* d_in, const int* in_sizes, int n_in,
                              void* d_out, int out_size, void* d_ws, size_t ws_size,
                              hipStream_t stream) {
    const void* x    = d_in[0];
    const int*  ei   = (const int*)d_in[1];
    const int*  srcE = ei;
    const int*  dstE = ei + NE;

    char* ws = (char*)d_ws;
    float* hA    = (float*)(ws + 0);
    float* hB    = (float*)(ws + 33554432);
    float* tvec  = (float*)(ws + 67108864);
    float* invc  = (float*)(ws + 67371008);
    float* q     = (float*)(ws + 100663296);
    float* r     = (float*)(ws + 100925440);
    float* score = (float*)(ws + 101187584);
    float* nm    = (float*)(ws + 101449728);
    int*   rowc  = (int*)  (ws + 101711872);
    int*   rp    = (int*)  (ws + 101974016);
    int*   bsum  = (int*)  (ws + 102236416);
    int*   fill  = (int*)  (ws + 102238464);
    int*   col   = (int*)  (ws + 102500608);
    float* g     = (float*)(ws + 104597760);
    float* gcnt  = (float*)(ws + 104614144);
    int*   flag  = (int*)  (ws + 104615936);
    float* wts   = (float*)(ws + 104616960);
    unsigned short* Wpack = (unsigned short*)(ws + 105179136);
    (void)in_sizes; (void)n_in; (void)out_size; (void)ws_size;

    const int O_Wl1 = 0,      O_bl1 = 16384,  O_Wr1 = 16512;
    const int O_Wl2 = 32896,  O_bl2 = 49280,  O_Wr2 = 49408;
    const int O_Wl3 = 65792,  O_bl3 = 82176,  O_Wr3 = 82304;
    const int O_Wl4 = 98688,  O_bl4 = 115072, O_Wr4 = 115200;
    const int O_Pr1 = 131584, O_pb1 = 131712, O_Po1 = 131713;
    const int O_Pr2 = 131841, O_pb2 = 131969, O_Po2 = 131970;
    const int O_W5  = 132098, O_b5  = 140290, O_W6 = 140354, O_b6 = 140482;

    CvtDesc d;
    const int srcIdx[22] = {4,5,6,7,8,9,10,11,12,13,14,15,16,17,18,19,20,21,22,23,24,25};
    const int nelems[22] = {16384,128,16384, 16384,128,16384, 16384,128,16384, 16384,128,16384,
                            128,1,128, 128,1,128, 8192,64,128,2};
    const int offs[22]   = {O_Wl1,O_bl1,O_Wr1, O_Wl2,O_bl2,O_Wr2, O_Wl3,O_bl3,O_Wr3, O_Wl4,O_bl4,O_Wr4,
                            O_Pr1,O_pb1,O_Po1, O_Pr2,O_pb2,O_Po2, O_W5,O_b5,O_W6,O_b6};
    for (int i = 0; i < 22; ++i) { d.src[i] = d_in[srcIdx[i]]; d.n[i] = nelems[i]; d.off[i] = offs[i]; }

    hipMemsetAsync(g, 0, (NG * HID + NG + 64) * 4, stream);

    k_detect <<<1, 256, 0, stream>>>((const unsigned short*)x, flag);
    k_cvt    <<<dim3(64, 22), 256, 0, stream>>>(d, wts, flag);
    k_packW  <<<512, 256, 0, stream>>>(wts, make_int4(O_Wl1, O_Wl2, O_Wl3, O_Wl4),
                                       make_int4(O_Wr1, O_Wr2, O_Wr3, O_Wr4), Wpack, rowc, fill);
    k_load_x <<<8192, 256, 0, stream>>>(x, hA, flag, NT * HID / 4, nm, dstE, rowc);

    k_scan1  <<<256, 256, 0, stream>>>(rowc, rp, bsum, invc);
    k_scan23 <<<256, 256, 0, stream>>>(rp, bsum);
    k_scatter<<<2048, 256, 0, stream>>>(srcE, dstE, rp, fill, col);

    // layer 1: x/hA -> hB (reads x directly when fp32 input)
    k_sage_plain<false><<<2048, 256, 0, stream>>>(hA, x, flag, nullptr, nm, invc, rp, col,
                                                  Wpack + 0 * 65536, wts + O_bl1, hB);
    // layer 2: hB -> hA  (+ fused pool-1 dots)
    k_sage_dots<<<2048, 256, 0, stream>>>(hB, nm, invc, rp, col,
                                          Wpack + 1 * 65536, wts + O_bl2, hA,
                                          wts + O_Pr1, wts + O_Po1, q, r);

    // pool 1 (k = 1024)
    k_score<<<256, 256, 0, stream>>>(q, r, wts + O_pb1, rp, col, score);
    k_topk <<<32, 256, 0, stream>>>(score, nm, tvec, 1024);
    k_invc <<<256, 256, 0, stream>>>(nm, rp, col, invc);

    // layer 3: hA (scaled by tvec) -> hB
    k_sage_plain<true><<<2048, 256, 0, stream>>>(hA, nullptr, flag, tvec, nm, invc, rp, col,
                                                 Wpack + 2 * 65536, wts + O_bl3, hB);
    // layer 4: hB -> hA  (+ fused pool-2 dots)
    k_sage_dots<<<2048, 256, 0, stream>>>(hB, nm, invc, rp, col,
                                          Wpack + 3 * 65536, wts + O_bl4, hA,
                                          wts + O_Pr2, wts + O_Po2, q, r);

    // pool 2 (k = 512)
    k_score<<<256, 256, 0, stream>>>(q, r, wts + O_pb2, rp, col, score);
    k_topk <<<32, 256, 0, stream>>>(score, nm, tvec, 512);

    // readout (h*t folded in)
    k_gsum<<<512, 256, 0, stream>>>(hA, tvec, nm, g, gcnt);
    k_mlp <<<32, 64, 0, stream>>>(g, gcnt, wts + O_W5, wts + O_b5, wts + O_W6, wts + O_b6, d_out, flag);
}